// Round 21
// baseline (502.497 us; speedup 1.0000x reference)
//
#include <hip/hip_runtime.h>
#include <math.h>

typedef __attribute__((ext_vector_type(8))) short short8;
typedef __attribute__((ext_vector_type(4))) float f32x4;

#define NCB 4
#define NE 1024
#define DIM 64
#define HW 16384
#define NPIX 131072
#define NWAVES 4096            // 1024 blocks * 4 waves
#define MSE_DENOM 8388608.0f   // NPIX*DIM
#define EPSF 1e-5f
#define CH1_BYTES 16384        // sweep chunk: 128 codes * 128B (plane-1 only)
#define NCH1 8                 // sweep chunks per codebook
#define CAP 1024               // candidate list capacity: >= NE -> NO drop possible

__device__ __forceinline__ unsigned short f2bf(float x) {  // RNE fp32->bf16
    unsigned u = __float_as_uint(x);
    u += 0x7fffu + ((u >> 16) & 1u);
    return (unsigned short)(u >> 16);
}
__device__ __forceinline__ float bf2f(unsigned short h) {  // exact bf16->fp32
    return __uint_as_float(((unsigned)h) << 16);
}

// ------- kernel 0: -0.5*||e||^2 per code + per-cb max ||e||^2 ------------
__global__ __launch_bounds__(64) void rvq_norms(const float* __restrict__ cb,
                                                float* __restrict__ nrmh,
                                                float* __restrict__ emax2) {
    int code = blockIdx.x * 64 + threadIdx.x;  // 0..4095
    const float4* row = reinterpret_cast<const float4*>(cb + (size_t)code * DIM);
    float s0 = 0.f, s1 = 0.f, s2 = 0.f, s3 = 0.f;
#pragma unroll
    for (int k = 0; k < 16; ++k) {
        float4 v = row[k];
        s0 = fmaf(v.x, v.x, s0); s1 = fmaf(v.y, v.y, s1);
        s2 = fmaf(v.z, v.z, s2); s3 = fmaf(v.w, v.w, s3);
    }
    float n2 = (s0 + s1) + (s2 + s3);
    nrmh[code] = -0.5f * n2;
    // positive floats are monotone as ints -> int atomicMax works
    atomicMax((int*)&emax2[blockIdx.x >> 4], __float_as_int(n2));
}

// ------- kernel 0b: pre-split codebook -> two images ---------------------
// compact gB1 [cb][code][128B, swizzled ^((code&7)<<4)]: sweep staging.
// full gBf [cb][code][split(3)][128B, LINEAR]: refine reads from global/L2.
__global__ __launch_bounds__(256) void rvq_presplit(const float* __restrict__ cb,
                                                    unsigned short* __restrict__ gB1,
                                                    unsigned short* __restrict__ gBf) {
    int blk = blockIdx.x;            // i*16 + c64
    int tid = threadIdx.x;
    int code64 = tid >> 2, dg = tid & 3;
    int c0 = (blk & 15) << 6;
    int i  = blk >> 4;
    int C  = c0 + code64;            // global code within codebook
    const float4* s4 = reinterpret_cast<const float4*>(
        cb + ((size_t)i * NE + C) * DIM + dg * 16);
    float v[16];
    {
        float4 q;
        q = s4[0]; v[0]=q.x; v[1]=q.y; v[2]=q.z; v[3]=q.w;
        q = s4[1]; v[4]=q.x; v[5]=q.y; v[6]=q.z; v[7]=q.w;
        q = s4[2]; v[8]=q.x; v[9]=q.y; v[10]=q.z; v[11]=q.w;
        q = s4[3]; v[12]=q.x; v[13]=q.y; v[14]=q.z; v[15]=q.w;
    }
    char* out1 = reinterpret_cast<char*>(gB1) + (size_t)i * 131072 + (size_t)C * 128;
    char* outf = reinterpret_cast<char*>(gBf) + (size_t)i * 393216 + (size_t)C * 384;
    int sw = (C & 7) << 4;
#pragma unroll
    for (int h = 0; h < 2; ++h) {
        short8 p1, p2, p3;
#pragma unroll
        for (int e = 0; e < 8; ++e) {
            float t = v[h * 8 + e];
            unsigned short u1 = f2bf(t); t -= bf2f(u1);
            unsigned short u2 = f2bf(t); t -= bf2f(u2);
            unsigned short u3 = f2bf(t);
            p1[e] = (short)u1; p2[e] = (short)u2; p3[e] = (short)u3;
        }
        int al = dg * 32 + h * 16;
        *reinterpret_cast<short8*>(out1 + (al ^ sw)) = p1;   // swizzled plane-1
        *reinterpret_cast<short8*>(outf + al)        = p1;   // linear full
        *reinterpret_cast<short8*>(outf + 128 + al)  = p2;
        *reinterpret_cast<short8*>(outf + 256 + al)  = p3;
    }
}

// async 16B/lane global->LDS: wave-uniform LDS base, per-lane global src.
__device__ __forceinline__ void gload16(const void* gsrc, void* ldst) {
    __builtin_amdgcn_global_load_lds(
        (const __attribute__((address_space(1))) unsigned int*)gsrc,
        (__attribute__((address_space(3))) unsigned int*)ldst, 16, 0, 0);
}

// ------- kernel 1: SINGLE-pass sound-bound RVQ ---------------------------
// R20 (two sweeps, passed, 430us) was latency-bound: 16 barrier-paced
// staging chunks/cb with only 4 MFMA/sub to hide them. This version merges
// the sweeps: ONE pass with a RUNNING per-row threshold — update maxv with
// the code's s1, push iff s1 >= maxv - margin. Running max <= final max
// -> pushed set is a SUPERSET of R20's validated sound final-threshold set
// (which contains the s_full argmax); CAP=1024 + per-code dedupe makes
// over-collection harmless (worst case = full refine scan = R14, never
// wrong). Chunk-boundary cross-lane max-reduce tightens the threshold
// progressively (raises running max -> still superset). Refine/outputs/
// residual path byte-identical to passing R20.
__global__ __launch_bounds__(256, 2) void rvq_main(
    const float* __restrict__ z, const unsigned short* __restrict__ gB1,
    const unsigned short* __restrict__ gBf,
    const float* __restrict__ nrmh, const float* __restrict__ emax2,
    const float* __restrict__ cb,
    float* __restrict__ out_zq, float* __restrict__ out_idx,
    unsigned* __restrict__ hist, float* __restrict__ msePartial)
{
    __shared__ uint4 sB[2][CH1_BYTES / 16];   // 32 KB sweep double buffer
    __shared__ int   sBest[4][32];
    __shared__ float sRn[4][32];
    __shared__ int   sList[4][CAP];           // 16 KB
    __shared__ int   sCnt[4];

    const int tid  = threadIdx.x;
    const int lane = tid & 63;
    const int wid  = tid >> 6;
    const int col  = lane & 15;   // A-row within tile / D-col (code)
    const int g    = lane >> 4;   // k-group (8 dims) / D row-group
    const int blockPix = blockIdx.x * 128;
    char* sBase = reinterpret_cast<char*>(sB);
    const int sw = (col & 7) << 4;
    const char* gB1b = reinterpret_cast<const char*>(gB1);
    const char* gBfb = reinterpret_cast<const char*>(gBf);

    // cb0 sweep-chunk0: issue before anything (z-load+split covers latency)
#pragma unroll
    for (int k = 0; k < 4; ++k)
        gload16(gB1b + k * 4096 + tid * 16, sBase + k * 4096 + tid * 16);

    size_t zb[2];
#pragma unroll
    for (int m = 0; m < 2; ++m) {
        int pf = blockPix + wid * 32 + m * 16 + col;
        zb[m] = (size_t)(pf >> 14) * 1048576 + (size_t)(pf & 16383);
    }

    float r[2][2][8];   // [m][kh][e], dim = kh*32 + g*8 + e
#pragma unroll
    for (int m = 0; m < 2; ++m)
#pragma unroll
        for (int kh = 0; kh < 2; ++kh)
#pragma unroll
            for (int e = 0; e < 8; ++e)
                r[m][kh][e] = z[zb[m] + (size_t)(kh * 32 + g * 8 + e) * HW];

    for (int i = 0; i < NCB; ++i) {
        const char* gB1i = gB1b + (size_t)i * 131072;
        const char* gBfi = gBfb + (size_t)i * 393216;
        const float* nrm_i = nrmh + i * NE;
        if (lane == 0) sCnt[wid] = 0;

        // bf16x3 split of r -> A-frags; fold in per-row ||r||^2
        short8 A[3][2][2];
        float rn2[2] = {0.f, 0.f};
#pragma unroll
        for (int m = 0; m < 2; ++m)
#pragma unroll
            for (int kh = 0; kh < 2; ++kh)
#pragma unroll
                for (int e = 0; e < 8; ++e) {
                    float t0 = r[m][kh][e];
                    rn2[m] = fmaf(t0, t0, rn2[m]);
                    float t = t0;
                    unsigned short u1 = f2bf(t); t -= bf2f(u1);
                    unsigned short u2 = f2bf(t); t -= bf2f(u2);
                    unsigned short u3 = f2bf(t);
                    A[0][m][kh][e] = (short)u1;
                    A[1][m][kh][e] = (short)u2;
                    A[2][m][kh][e] = (short)u3;
                }
#pragma unroll
        for (int m = 0; m < 2; ++m) {   // reduce over the 4 g-lanes (same col)
            rn2[m] += __shfl_xor(rn2[m], 16, 64);
            rn2[m] += __shfl_xor(rn2[m], 32, 64);
        }
        if (lane < 16) { sRn[wid][lane] = rn2[0]; sRn[wid][16 + lane] = rn2[1]; }

        // sound per-row margin (R20-validated: 2.6B with bf16 2^-8 bound)
        float margin[2][4];
        {
            float en = sqrtf(emax2[i]);
#pragma unroll
            for (int m = 0; m < 2; ++m)
#pragma unroll
                for (int rr = 0; rr < 4; ++rr) {
                    float rn = sqrtf(sRn[wid][m * 16 + g * 4 + rr]);
                    margin[m][rr] = 0.0205f * rn * en + 8e-3f;
                }
        }

        float maxv[2][4];
#pragma unroll
        for (int m = 0; m < 2; ++m)
#pragma unroll
            for (int rr = 0; rr < 4; ++rr) maxv[m][rr] = -3.4e38f;

        // ------- single sweep: running-threshold max + candidate push ----
        for (int c = 0; c < NCH1; ++c) {
            __syncthreads();
            if (c < NCH1 - 1) {   // issue next chunk into the freed buffer
                const char* gc = gB1i + (size_t)(c + 1) * CH1_BYTES;
                char* sbn = sBase + ((c + 1) & 1) * CH1_BYTES;
#pragma unroll
                for (int k = 0; k < 4; ++k)
                    gload16(gc + k * 4096 + tid * 16, sbn + k * 4096 + tid * 16);
            }
            const char* sbc = sBase + (c & 1) * CH1_BYTES;
#pragma unroll
            for (int sub = 0; sub < 8; ++sub) {
                const int code = (sub << 4) + col;
                float nh = nrm_i[(c << 7) + code];
                short8 B0 = *reinterpret_cast<const short8*>(
                    sbc + ((((code << 7) + (g << 4))) ^ sw));
                short8 B1 = *reinterpret_cast<const short8*>(
                    sbc + ((((code << 7) + 64 + (g << 4))) ^ sw));
                f32x4 acc0, acc1;
#pragma unroll
                for (int rr = 0; rr < 4; ++rr) { acc0[rr] = nh; acc1[rr] = nh; }
                __builtin_amdgcn_s_setprio(1);
                acc0 = __builtin_amdgcn_mfma_f32_16x16x32_bf16(A[0][0][0], B0, acc0, 0, 0, 0);
                acc1 = __builtin_amdgcn_mfma_f32_16x16x32_bf16(A[0][1][0], B0, acc1, 0, 0, 0);
                acc0 = __builtin_amdgcn_mfma_f32_16x16x32_bf16(A[0][0][1], B1, acc0, 0, 0, 0);
                acc1 = __builtin_amdgcn_mfma_f32_16x16x32_bf16(A[0][1][1], B1, acc1, 0, 0, 0);
                __builtin_amdgcn_s_setprio(0);
                // update running max FIRST, then superset push check
                bool anyhit = false;
#pragma unroll
                for (int rr = 0; rr < 4; ++rr) {
                    maxv[0][rr] = fmaxf(maxv[0][rr], acc0[rr]);
                    maxv[1][rr] = fmaxf(maxv[1][rr], acc1[rr]);
                    anyhit |= (acc0[rr] >= maxv[0][rr] - margin[0][rr]);
                    anyhit |= (acc1[rr] >= maxv[1][rr] - margin[1][rr]);
                }
                unsigned long long mb = __ballot(anyhit);
                if (mb) {   // dedupe across the 4 g-lanes sharing this col
                    unsigned long long colmask = 0x0001000100010001ULL << col;
                    bool push = anyhit &&
                        !(mb & colmask & ((lane == 0) ? 0ULL : ((1ULL << lane) - 1)));
                    if (push) {
                        int p = atomicAdd(&sCnt[wid], 1);
                        if (p < CAP) sList[wid][p] = (c << 7) + code;  // p<1024 always
                    }
                }
            }
            // chunk-boundary tighten: raise running max toward row-global
#pragma unroll
            for (int m = 0; m < 2; ++m)
#pragma unroll
                for (int rr = 0; rr < 4; ++rr) {
#pragma unroll
                    for (int off = 1; off < 16; off <<= 1)
                        maxv[m][rr] = fmaxf(maxv[m][rr], __shfl_xor(maxv[m][rr], off, 64));
                }
        }

        // next cb's sweep chunk0: issue NOW (refine+epilogue cover latency).
        // buf0's last readers = compute(c=6); all waves passed the c=7
        // barrier -> safe.
        if (i < NCB - 1) {
            const char* gn = gB1b + (size_t)(i + 1) * 131072;
#pragma unroll
            for (int k = 0; k < 4; ++k)
                gload16(gn + k * 4096 + tid * 16, sBase + k * 4096 + tid * 16);
        }

        // ---------------- refine: full 6-product on candidate union -----
        float bestv[2][4]; int besti[2][4];
#pragma unroll
        for (int m = 0; m < 2; ++m)
#pragma unroll
            for (int rr = 0; rr < 4; ++rr) { bestv[m][rr] = -3.4e38f; besti[m][rr] = 0x7fffffff; }

        int ncand = sCnt[wid]; if (ncand > CAP) ncand = CAP;
        for (int b = 0; b < ncand; b += 16) {
            int ci = b + col;
            int code = sList[wid][ci < ncand ? ci : 0];  // pad = dup (harmless)
            const char* base = gBfi + (size_t)code * 384;
            short8 B[3][2];
#pragma unroll
            for (int s = 0; s < 3; ++s) {
                B[s][0] = *reinterpret_cast<const short8*>(base + s * 128 + (g << 4));
                B[s][1] = *reinterpret_cast<const short8*>(base + s * 128 + 64 + (g << 4));
            }
            float nh = nrm_i[code];
            f32x4 acc0, acc1;
#pragma unroll
            for (int rr = 0; rr < 4; ++rr) { acc0[rr] = nh; acc1[rr] = nh; }
            __builtin_amdgcn_s_setprio(1);
#pragma unroll
            for (int sb = 0; sb < 3; ++sb) {   // EXACT R14 chain order
#pragma unroll
                for (int sa = 0; sa < 3 - sb; ++sa) {
                    acc0 = __builtin_amdgcn_mfma_f32_16x16x32_bf16(A[sa][0][0], B[sb][0], acc0, 0, 0, 0);
                    acc1 = __builtin_amdgcn_mfma_f32_16x16x32_bf16(A[sa][1][0], B[sb][0], acc1, 0, 0, 0);
                    acc0 = __builtin_amdgcn_mfma_f32_16x16x32_bf16(A[sa][0][1], B[sb][1], acc0, 0, 0, 0);
                    acc1 = __builtin_amdgcn_mfma_f32_16x16x32_bf16(A[sa][1][1], B[sb][1], acc1, 0, 0, 0);
                }
            }
            __builtin_amdgcn_s_setprio(0);
#pragma unroll
            for (int rr = 0; rr < 4; ++rr) {
                float s0 = acc0[rr];
                if (s0 > bestv[0][rr] || (s0 == bestv[0][rr] && code < besti[0][rr])) {
                    bestv[0][rr] = s0; besti[0][rr] = code;
                }
                float s1 = acc1[rr];
                if (s1 > bestv[1][rr] || (s1 == bestv[1][rr] && code < besti[1][rr])) {
                    bestv[1][rr] = s1; besti[1][rr] = code;
                }
            }
        }

        // cross-lane argmax within each 16-lane group, idx tie-break
#pragma unroll
        for (int m = 0; m < 2; ++m)
#pragma unroll
            for (int rr = 0; rr < 4; ++rr) {
                float v = bestv[m][rr]; int ix = besti[m][rr];
#pragma unroll
                for (int off = 1; off < 16; off <<= 1) {
                    float ov = __shfl_xor(v, off, 64);
                    int   oi = __shfl_xor(ix, off, 64);
                    if (ov > v || (ov == v && oi < ix)) { v = ov; ix = oi; }
                }
                besti[m][rr] = ix;
            }
        // wave-private exchange (same-wave LDS ordering; no barrier needed)
        if (col == 0) {
#pragma unroll
            for (int m = 0; m < 2; ++m)
#pragma unroll
                for (int rr = 0; rr < 4; ++rr)
                    sBest[wid][m * 16 + g * 4 + rr] = besti[m][rr];
        }

        const float* cbi = cb + (size_t)i * NE * DIM;
        if (lane < 16) {  // idx output + histogram, one writer per row
#pragma unroll
            for (int m = 0; m < 2; ++m) {
                int pfr = blockPix + wid * 32 + m * 16 + lane;
                int bb = pfr >> 14, yy = (pfr >> 7) & 127, xx = pfr & 127;
                int bi = sBest[wid][m * 16 + lane];
                size_t off = (size_t)bb * 65536 + (size_t)(yy >> 2) * 2048
                           + (size_t)(xx >> 2) * 64
                           + (size_t)(((yy & 3) << 2) + (xx & 3)) * 4 + (size_t)i;
                out_idx[off] = (float)bi;
                atomicAdd(&hist[i * NE + bi], 1u);
            }
        }

        // residual update from ORIGINAL fp32 codebook (keeps r exact)
#pragma unroll
        for (int m = 0; m < 2; ++m) {
            const int best = sBest[wid][m * 16 + col];
            const float* er = cbi + (size_t)best * DIM;
#pragma unroll
            for (int kh = 0; kh < 2; ++kh) {
                const float4* e4 = reinterpret_cast<const float4*>(er + kh * 32 + g * 8);
                float4 q0 = e4[0], q1 = e4[1];
                r[m][kh][0] -= q0.x; r[m][kh][1] -= q0.y;
                r[m][kh][2] -= q0.z; r[m][kh][3] -= q0.w;
                r[m][kh][4] -= q1.x; r[m][kh][5] -= q1.y;
                r[m][kh][6] -= q1.z; r[m][kh][7] -= q1.w;
            }
        }

        // MSE partial: (z_q - r_old)^2 = r_new^2
        float s = 0.f;
#pragma unroll
        for (int m = 0; m < 2; ++m)
#pragma unroll
            for (int kh = 0; kh < 2; ++kh)
#pragma unroll
                for (int e = 0; e < 8; ++e) s = fmaf(r[m][kh][e], r[m][kh][e], s);
#pragma unroll
        for (int d_ = 32; d_ > 0; d_ >>= 1) s += __shfl_down(s, d_, 64);
        if (lane == 0) msePartial[i * NWAVES + blockIdx.x * 4 + wid] = s;
    }

    // epilogue: z_q = z - r_final (telescoped straight-through sum)
#pragma unroll
    for (int m = 0; m < 2; ++m)
#pragma unroll
        for (int kh = 0; kh < 2; ++kh)
#pragma unroll
            for (int e = 0; e < 8; ++e) {
                size_t o = zb[m] + (size_t)(kh * 32 + g * 8 + e) * HW;
                out_zq[o] = z[o] - r[m][kh][e];
            }
}

// ---------------- kernel 2: deterministic loss finalize ----------------
__global__ __launch_bounds__(1024) void rvq_finalize(
    const unsigned* __restrict__ hist, const float* __restrict__ msePartial,
    float* __restrict__ out_loss)
{
    __shared__ float red[1024];
    int t = threadIdx.x;
    float loss = 0.f;
    for (int i = 0; i < NCB; ++i) {
        float cnt = (float)hist[i * NE + t];
        float prob = (cnt + EPSF) / (131072.0f + EPSF * 1024.0f);
        red[t] = -prob * logf(prob + EPSF);
        __syncthreads();
        for (int s = 512; s > 0; s >>= 1) { if (t < s) red[t] += red[t + s]; __syncthreads(); }
        float entropy = red[0];
        __syncthreads();
        float acc = 0.f;
#pragma unroll
        for (int k = 0; k < 4; ++k) acc += msePartial[i * NWAVES + k * 1024 + t];
        red[t] = acc;
        __syncthreads();
        for (int s = 512; s > 0; s >>= 1) { if (t < s) red[t] += red[t + s]; __syncthreads(); }
        float mse_sum = red[0];
        __syncthreads();
        loss += 0.25f * (mse_sum / MSE_DENOM) + 0.01f * (logf(1024.0f) - entropy);
    }
    if (t == 0) out_loss[0] = loss;
}

extern "C" void kernel_launch(void* const* d_in, const int* in_sizes, int n_in,
                              void* d_out, int out_size, void* d_ws, size_t ws_size,
                              hipStream_t stream) {
    const float* z  = (const float*)d_in[0];
    const float* cb = (const float*)d_in[1];

    float* out      = (float*)d_out;
    float* out_zq   = out;                    // 8388608
    float* out_loss = out + 8388608;          // 1
    float* out_idx  = out + 8388609;          // 524288 (indices as float)

    unsigned* hist        = (unsigned*)d_ws;                          // 16 KB
    float*    emax2       = (float*)((char*)d_ws + 16384);            // 16 B (zeroed)
    float*    nrmh        = (float*)((char*)d_ws + 32768);            // 16 KB
    float*    msePartial  = (float*)((char*)d_ws + 49152);            // 64 KB
    unsigned short* gB1   = (unsigned short*)((char*)d_ws + 131072);  // 512 KB compact
    unsigned short* gBf   = (unsigned short*)((char*)d_ws + 655360);  // 1.5 MB full

    hipMemsetAsync(d_ws, 0, 16448, stream);   // zero histogram + emax2
    rvq_norms<<<64, 64, 0, stream>>>(cb, nrmh, emax2);
    rvq_presplit<<<64, 256, 0, stream>>>(cb, gB1, gBf);
    rvq_main<<<1024, 256, 0, stream>>>(z, gB1, gBf, nrmh, emax2, cb,
                                       out_zq, out_idx, hist, msePartial);
    rvq_finalize<<<1, 1024, 0, stream>>>(hist, msePartial, out_loss);
}

// Round 22
// 382.005 us; speedup vs baseline: 1.3154x; 1.3154x over previous
//
#include <hip/hip_runtime.h>
#include <math.h>

typedef __attribute__((ext_vector_type(8))) short short8;
typedef __attribute__((ext_vector_type(4))) float f32x4;

#define NCB 4
#define NE 1024
#define DIM 64
#define HW 16384
#define NPIX 131072
#define NWAVES 4096            // 1024 blocks * 4 waves
#define MSE_DENOM 8388608.0f   // NPIX*DIM
#define EPSF 1e-5f
#define CHUNK_BYTES 24576      // 3 splits * 64 codes * 64 dims * 2B
#define CHUNK_SHORTS 12288
#define NCHUNK 16              // chunks per codebook

__device__ __forceinline__ unsigned short f2bf(float x) {  // RNE fp32->bf16
    unsigned u = __float_as_uint(x);
    u += 0x7fffu + ((u >> 16) & 1u);
    return (unsigned short)(u >> 16);
}
__device__ __forceinline__ float bf2f(unsigned short h) {  // exact bf16->fp32
    return __uint_as_float(((unsigned)h) << 16);
}

// ------------- kernel 0: -0.5*||e||^2 per code (fp32, exact) -------------
__global__ __launch_bounds__(64) void rvq_norms(const float* __restrict__ cb,
                                                float* __restrict__ nrmh) {
    int code = blockIdx.x * 64 + threadIdx.x;  // 0..4095
    const float4* row = reinterpret_cast<const float4*>(cb + (size_t)code * DIM);
    float s0 = 0.f, s1 = 0.f, s2 = 0.f, s3 = 0.f;
#pragma unroll
    for (int k = 0; k < 16; ++k) {
        float4 v = row[k];
        s0 = fmaf(v.x, v.x, s0); s1 = fmaf(v.y, v.y, s1);
        s2 = fmaf(v.z, v.z, s2); s3 = fmaf(v.w, v.w, s3);
    }
    nrmh[code] = -0.5f * ((s0 + s1) + (s2 + s3));
}

// ------------- kernel 0b: pre-split codebook -> swizzled bf16x3 image ----
// R5-validated layout: [cb i][chunk c(64 codes)] 24KB blobs, 3 planes of
// 8192B, addr=(code*128+dg*32+h*16)^((code&7)<<4). Byte-identical to the
// main kernel's LDS chunk buffer.
__global__ __launch_bounds__(256) void rvq_presplit(const float* __restrict__ cb,
                                                    unsigned short* __restrict__ gB) {
    int blk = blockIdx.x;            // i*16 + c
    int tid = threadIdx.x;
    int code = tid >> 2, dg = tid & 3;
    int c0 = (blk & 15) << 6;
    int i  = blk >> 4;
    const float4* s4 = reinterpret_cast<const float4*>(
        cb + ((size_t)i * NE + c0 + code) * DIM + dg * 16);
    float v[16];
    {
        float4 q;
        q = s4[0]; v[0]=q.x; v[1]=q.y; v[2]=q.z; v[3]=q.w;
        q = s4[1]; v[4]=q.x; v[5]=q.y; v[6]=q.z; v[7]=q.w;
        q = s4[2]; v[8]=q.x; v[9]=q.y; v[10]=q.z; v[11]=q.w;
        q = s4[3]; v[12]=q.x; v[13]=q.y; v[14]=q.z; v[15]=q.w;
    }
    char* outc = reinterpret_cast<char*>(gB + (size_t)blk * CHUNK_SHORTS);
    int linbase = code * 128 + dg * 32;
    int sw = (code & 7) << 4;
#pragma unroll
    for (int h = 0; h < 2; ++h) {
        short8 p1, p2, p3;
#pragma unroll
        for (int e = 0; e < 8; ++e) {
            float t = v[h * 8 + e];
            unsigned short u1 = f2bf(t); t -= bf2f(u1);
            unsigned short u2 = f2bf(t); t -= bf2f(u2);
            unsigned short u3 = f2bf(t);
            p1[e] = (short)u1; p2[e] = (short)u2; p3[e] = (short)u3;
        }
        int a = (linbase + h * 16) ^ sw;
        *reinterpret_cast<short8*>(outc + a)         = p1;
        *reinterpret_cast<short8*>(outc + 8192 + a)  = p2;
        *reinterpret_cast<short8*>(outc + 16384 + a) = p3;
    }
}

// async 16B/lane global->LDS: wave-uniform LDS base, per-lane global src.
__device__ __forceinline__ void gload16(const void* gsrc, void* ldst) {
    __builtin_amdgcn_global_load_lds(
        (const __attribute__((address_space(1))) unsigned int*)gsrc,
        (__attribute__((address_space(3))) unsigned int*)ldst, 16, 0, 0);
}

// ------------- kernel 1: MFMA RVQ, M=32, double-buffer (best: R14) -------
// 1024 blocks x 4 waves, (256,2). FINAL configuration — the validated
// 382us kernel. Nine structural variants (counted vmcnt, buffer depth,
// chunk size, barrier-free per-wave staging, B-prefetch, 6-chain ILP,
// candidate filtering) all landed in [382, 502]us: the plateau is the
// intersection of the register-bracket wall (M=32 state spills below the
// 256-reg bracket) and the occupancy wall (2 waves/SIMD can't hide the
// per-chunk barrier drain). Per chunk: __syncthreads (drains own vmcnt ->
// all waves' gloads(c) landed; compute(c-1) done = write target free);
// issue gloads(c+1); compute (4 subs x [6 ds_read_b128 + 24 MFMA,
// K-halves chained into 2 acc chains]). s = r.e - 0.5||e||^2 in-MFMA;
// argmax s == argmin dist; strict-> scan + idx tie-break = jnp.argmin.
__global__ __launch_bounds__(256, 2) void rvq_main(
    const float* __restrict__ z, const unsigned short* __restrict__ gB,
    const float* __restrict__ nrmh, const float* __restrict__ cb,
    float* __restrict__ out_zq, float* __restrict__ out_idx,
    unsigned* __restrict__ hist, float* __restrict__ msePartial)
{
    __shared__ uint4 sB[2][CHUNK_BYTES / 16];   // 48 KB double buffer
    __shared__ int   sBest[4][32];

    const int tid  = threadIdx.x;
    const int lane = tid & 63;
    const int wid  = tid >> 6;
    const int col  = lane & 15;   // A-row within tile / D-col (code)
    const int g    = lane >> 4;   // k-group (8 dims) / D row-group
    const int blockPix = blockIdx.x * 128;
    char* sBase = reinterpret_cast<char*>(sB);
    const int sw = (col & 7) << 4;

    // cb0 chunk0: issue before anything else (z-load+split covers latency)
#pragma unroll
    for (int k = 0; k < 6; ++k)
        gload16(reinterpret_cast<const char*>(gB) + k * 4096 + tid * 16,
                sBase + k * 4096 + tid * 16);

    size_t zb[2];
#pragma unroll
    for (int m = 0; m < 2; ++m) {
        int pf = blockPix + wid * 32 + m * 16 + col;
        zb[m] = (size_t)(pf >> 14) * 1048576 + (size_t)(pf & 16383);
    }

    float r[2][2][8];   // [m][kh][e], dim = kh*32 + g*8 + e
#pragma unroll
    for (int m = 0; m < 2; ++m)
#pragma unroll
        for (int kh = 0; kh < 2; ++kh)
#pragma unroll
            for (int e = 0; e < 8; ++e)
                r[m][kh][e] = z[zb[m] + (size_t)(kh * 32 + g * 8 + e) * HW];

    for (int i = 0; i < NCB; ++i) {
        const char* gBi = reinterpret_cast<const char*>(gB) + (size_t)i * NCHUNK * CHUNK_BYTES;
        const float* nrm_i = nrmh + i * NE;

        // bf16x3 split of r -> A-frags (once per codebook)
        short8 A[3][2][2];
#pragma unroll
        for (int m = 0; m < 2; ++m)
#pragma unroll
            for (int kh = 0; kh < 2; ++kh)
#pragma unroll
                for (int e = 0; e < 8; ++e) {
                    float t = r[m][kh][e];
                    unsigned short u1 = f2bf(t); t -= bf2f(u1);
                    unsigned short u2 = f2bf(t); t -= bf2f(u2);
                    unsigned short u3 = f2bf(t);
                    A[0][m][kh][e] = (short)u1;
                    A[1][m][kh][e] = (short)u2;
                    A[2][m][kh][e] = (short)u3;
                }

        float maxv[2][4]; int maxi[2][4];
#pragma unroll
        for (int m = 0; m < 2; ++m)
#pragma unroll
            for (int rr = 0; rr < 4; ++rr) { maxv[m][rr] = -3.4e38f; maxi[m][rr] = 0; }

        for (int c = 0; c < NCHUNK; ++c) {
            // drains own vmcnt (gloads(c) covered by compute(c-1)) + syncs:
            // after this, buf[c&1] is fully populated for ALL waves, and
            // buf[(c+1)&1]'s last readers (compute(c-1)) are all done.
            __syncthreads();
            if (c < NCHUNK - 1) {   // issue next chunk into the freed buffer
                const char* gc = gBi + (size_t)(c + 1) * CHUNK_BYTES;
                char* sbn = sBase + ((c + 1) & 1) * CHUNK_BYTES;
#pragma unroll
                for (int k = 0; k < 6; ++k)
                    gload16(gc + k * 4096 + tid * 16, sbn + k * 4096 + tid * 16);
            }
            const char* sbc = sBase + (c & 1) * CHUNK_BYTES;

#pragma unroll
            for (int sub = 0; sub < 4; ++sub) {
                const int code = (sub << 4) + col;
                float nh = nrm_i[(c << 6) + code];
                f32x4 acc[2];
#pragma unroll
                for (int rr = 0; rr < 4; ++rr) { acc[0][rr] = nh; acc[1][rr] = nh; }

                __builtin_amdgcn_s_setprio(1);
#pragma unroll
                for (int sb = 0; sb < 3; ++sb) {   // B-split-major: 2 B regs live
                    short8 B0 = *reinterpret_cast<const short8*>(
                        sbc + sb * 8192 + ((((code << 7) + (g << 4))) ^ sw));
                    short8 B1 = *reinterpret_cast<const short8*>(
                        sbc + sb * 8192 + ((((code << 7) + 64 + (g << 4))) ^ sw));
#pragma unroll
                    for (int sa = 0; sa < 3 - sb; ++sa) {   // products with sa+sb<=2
                        acc[0] = __builtin_amdgcn_mfma_f32_16x16x32_bf16(A[sa][0][0], B0, acc[0], 0, 0, 0);
                        acc[1] = __builtin_amdgcn_mfma_f32_16x16x32_bf16(A[sa][1][0], B0, acc[1], 0, 0, 0);
                        acc[0] = __builtin_amdgcn_mfma_f32_16x16x32_bf16(A[sa][0][1], B1, acc[0], 0, 0, 0);
                        acc[1] = __builtin_amdgcn_mfma_f32_16x16x32_bf16(A[sa][1][1], B1, acc[1], 0, 0, 0);
                    }
                }
                __builtin_amdgcn_s_setprio(0);

#pragma unroll
                for (int m = 0; m < 2; ++m)
#pragma unroll
                    for (int rr = 0; rr < 4; ++rr) {
                        float s = acc[m][rr];      // argmax s == argmin dist
                        if (s > maxv[m][rr]) { maxv[m][rr] = s; maxi[m][rr] = (c << 6) + code; }
                    }
            }
        }

        // next codebook's chunk0: issue NOW so the epilogue covers latency.
        // buf0's last readers were compute(14) — all waves passed the c=15
        // barrier, so they're done.
        if (i < NCB - 1) {
            const char* gn = reinterpret_cast<const char*>(gB)
                           + (size_t)(i + 1) * NCHUNK * CHUNK_BYTES;
#pragma unroll
            for (int k = 0; k < 6; ++k)
                gload16(gn + k * 4096 + tid * 16, sBase + k * 4096 + tid * 16);
        }

        // cross-lane argmax within each 16-lane group, idx tie-break
#pragma unroll
        for (int m = 0; m < 2; ++m)
#pragma unroll
            for (int rr = 0; rr < 4; ++rr) {
                float v = maxv[m][rr]; int ix = maxi[m][rr];
#pragma unroll
                for (int off = 1; off < 16; off <<= 1) {
                    float ov = __shfl_xor(v, off, 64);
                    int   oi = __shfl_xor(ix, off, 64);
                    if (ov > v || (ov == v && oi < ix)) { v = ov; ix = oi; }
                }
                maxi[m][rr] = ix;
            }
        // wave-private exchange (same-wave LDS ordering; no barrier needed)
        if (col == 0) {
#pragma unroll
            for (int m = 0; m < 2; ++m)
#pragma unroll
                for (int rr = 0; rr < 4; ++rr)
                    sBest[wid][m * 16 + g * 4 + rr] = maxi[m][rr];
        }

        const float* cbi = cb + (size_t)i * NE * DIM;
        if (lane < 16) {  // idx output + histogram, one writer per row
#pragma unroll
            for (int m = 0; m < 2; ++m) {
                int pfr = blockPix + wid * 32 + m * 16 + lane;
                int bb = pfr >> 14, yy = (pfr >> 7) & 127, xx = pfr & 127;
                int bi = sBest[wid][m * 16 + lane];
                size_t off = (size_t)bb * 65536 + (size_t)(yy >> 2) * 2048
                           + (size_t)(xx >> 2) * 64
                           + (size_t)(((yy & 3) << 2) + (xx & 3)) * 4 + (size_t)i;
                out_idx[off] = (float)bi;
                atomicAdd(&hist[i * NE + bi], 1u);
            }
        }

        // residual update from ORIGINAL fp32 codebook (keeps r exact)
#pragma unroll
        for (int m = 0; m < 2; ++m) {
            const int best = sBest[wid][m * 16 + col];
            const float* er = cbi + (size_t)best * DIM;
#pragma unroll
            for (int kh = 0; kh < 2; ++kh) {
                const float4* e4 = reinterpret_cast<const float4*>(er + kh * 32 + g * 8);
                float4 q0 = e4[0], q1 = e4[1];
                r[m][kh][0] -= q0.x; r[m][kh][1] -= q0.y;
                r[m][kh][2] -= q0.z; r[m][kh][3] -= q0.w;
                r[m][kh][4] -= q1.x; r[m][kh][5] -= q1.y;
                r[m][kh][6] -= q1.z; r[m][kh][7] -= q1.w;
            }
        }

        // MSE partial: (z_q - r_old)^2 = r_new^2
        float s = 0.f;
#pragma unroll
        for (int m = 0; m < 2; ++m)
#pragma unroll
            for (int kh = 0; kh < 2; ++kh)
#pragma unroll
                for (int e = 0; e < 8; ++e) s = fmaf(r[m][kh][e], r[m][kh][e], s);
#pragma unroll
        for (int d_ = 32; d_ > 0; d_ >>= 1) s += __shfl_down(s, d_, 64);
        if (lane == 0) msePartial[i * NWAVES + blockIdx.x * 4 + wid] = s;
    }

    // epilogue: z_q = z - r_final (telescoped straight-through sum)
#pragma unroll
    for (int m = 0; m < 2; ++m)
#pragma unroll
        for (int kh = 0; kh < 2; ++kh)
#pragma unroll
            for (int e = 0; e < 8; ++e) {
                size_t o = zb[m] + (size_t)(kh * 32 + g * 8 + e) * HW;
                out_zq[o] = z[o] - r[m][kh][e];
            }
}

// ---------------- kernel 2: deterministic loss finalize ----------------
__global__ __launch_bounds__(1024) void rvq_finalize(
    const unsigned* __restrict__ hist, const float* __restrict__ msePartial,
    float* __restrict__ out_loss)
{
    __shared__ float red[1024];
    int t = threadIdx.x;
    float loss = 0.f;
    for (int i = 0; i < NCB; ++i) {
        float cnt = (float)hist[i * NE + t];
        float prob = (cnt + EPSF) / (131072.0f + EPSF * 1024.0f);
        red[t] = -prob * logf(prob + EPSF);
        __syncthreads();
        for (int s = 512; s > 0; s >>= 1) { if (t < s) red[t] += red[t + s]; __syncthreads(); }
        float entropy = red[0];
        __syncthreads();
        float acc = 0.f;
#pragma unroll
        for (int k = 0; k < 4; ++k) acc += msePartial[i * NWAVES + k * 1024 + t];
        red[t] = acc;
        __syncthreads();
        for (int s = 512; s > 0; s >>= 1) { if (t < s) red[t] += red[t + s]; __syncthreads(); }
        float mse_sum = red[0];
        __syncthreads();
        loss += 0.25f * (mse_sum / MSE_DENOM) + 0.01f * (logf(1024.0f) - entropy);
    }
    if (t == 0) out_loss[0] = loss;
}

extern "C" void kernel_launch(void* const* d_in, const int* in_sizes, int n_in,
                              void* d_out, int out_size, void* d_ws, size_t ws_size,
                              hipStream_t stream) {
    const float* z  = (const float*)d_in[0];
    const float* cb = (const float*)d_in[1];

    float* out      = (float*)d_out;
    float* out_zq   = out;                    // 8388608
    float* out_loss = out + 8388608;          // 1
    float* out_idx  = out + 8388609;          // 524288 (indices as float)

    unsigned* hist        = (unsigned*)d_ws;                         // 16 KB
    float*    nrmh        = (float*)((char*)d_ws + 16384);           // 16 KB
    float*    msePartial  = (float*)((char*)d_ws + 32768);           // 64 KB (4*4096 f32)
    unsigned short* gB    = (unsigned short*)((char*)d_ws + 163840); // 1.5 MB pre-split image

    hipMemsetAsync(d_ws, 0, 16384, stream);   // zero histogram (deterministic)
    rvq_norms<<<64, 64, 0, stream>>>(cb, nrmh);
    rvq_presplit<<<64, 256, 0, stream>>>(cb, gB);
    rvq_main<<<1024, 256, 0, stream>>>(z, gB, nrmh, cb, out_zq, out_idx, hist, msePartial);
    rvq_finalize<<<1, 1024, 0, stream>>>(hist, msePartial, out_loss);
}